// Round 3
// baseline (442.497 us; speedup 1.0000x reference)
//
#include <hip/hip_runtime.h>
#include <math.h>

#define S_LEN 3072
#define DIM 1536
#define NHEADS 16
#define HDIM 96
#define NPAIR 48

typedef __attribute__((ext_vector_type(8))) _Float16 half8;
typedef __attribute__((ext_vector_type(4))) _Float16 half4v;
typedef __attribute__((ext_vector_type(2))) _Float16 half2v;
typedef __attribute__((ext_vector_type(4))) float f32x4;

__device__ inline void gload16(const void* g, void* l) {
    __builtin_amdgcn_global_load_lds(
        (const __attribute__((address_space(1))) void*)g,
        (__attribute__((address_space(3))) void*)l, 16, 0, 0);
}

// ---------------- prep: fp32 -> fp16 elementwise ----------------
__global__ __launch_bounds__(256)
void convert_f32_f16(const float* __restrict__ src, _Float16* __restrict__ dst, int n4)
{
    int i = blockIdx.x * 256 + threadIdx.x;
    if (i < n4) {
        float4 v = *(const float4*)&src[(size_t)i * 4];
        half4v h = { (_Float16)v.x, (_Float16)v.y, (_Float16)v.z, (_Float16)v.w };
        *(half4v*)&dst[(size_t)i * 4] = h;
    }
}

// ---------------- prep: W[k][n] fp32 -> Wt[n][k] fp16 (64x64 LDS tiles) ----------------
__global__ __launch_bounds__(256)
void transpose_w(const float* __restrict__ w0, const float* __restrict__ w1,
                 const float* __restrict__ w2, const float* __restrict__ w3,
                 _Float16* __restrict__ wt)
{
    __shared__ _Float16 t[64][68];
    const int z = blockIdx.z;
    const float* W = (z == 0) ? w0 : (z == 1) ? w1 : (z == 2) ? w2 : w3;
    _Float16* O = wt + (size_t)z * DIM * DIM;
    const int k0 = blockIdx.y * 64, n0 = blockIdx.x * 64;
    const int tid = threadIdx.x;
    const int r = tid >> 4, c4 = (tid & 15) * 4;
#pragma unroll
    for (int g = 0; g < 4; g++) {
        int kk = r + g * 16;
        float4 v = *(const float4*)&W[(size_t)(k0 + kk) * DIM + n0 + c4];
        t[c4 + 0][kk] = (_Float16)v.x; t[c4 + 1][kk] = (_Float16)v.y;
        t[c4 + 2][kk] = (_Float16)v.z; t[c4 + 3][kk] = (_Float16)v.w;
    }
    __syncthreads();
    const int nr = tid >> 2, ks = (tid & 3) * 16;
#pragma unroll
    for (int s = 0; s < 4; s++)
        *(ushort4*)&O[(size_t)(n0 + nr) * DIM + k0 + ks + s * 4] =
            *(ushort4*)&t[nr][ks + s * 4];
}

// ---------------- fp16 MFMA GEMM with fused RoPE epilogue ----------------
// QKV=true: q,k written [head][s][hd] with RoPE applied; v written TRANSPOSED [head][hd][s].
template<bool QKV>
__global__ __launch_bounds__(256)
void gemm_f16(const _Float16* __restrict__ X,
              const _Float16* __restrict__ W0t, const _Float16* __restrict__ W1t,
              const _Float16* __restrict__ W2t,
              const float* __restrict__ B0, const float* __restrict__ B1,
              const float* __restrict__ B2,
              const float* __restrict__ fc, const float* __restrict__ fs,
              void* __restrict__ outv)
{
    __shared__ __align__(16) _Float16 As[128][64];   // 16 KB
    __shared__ __align__(16) _Float16 Bs[128][64];   // 16 KB

    const int tid = threadIdx.x;
    const int w = tid >> 6, lane = tid & 63;
    const int ln = lane & 15, quad = lane >> 4;
    const int bz = blockIdx.z;
    const _Float16* Wt = W0t; const float* bias = B0;
    if (QKV) { if (bz == 1) { Wt = W1t; bias = B1; } else if (bz == 2) { Wt = W2t; bias = B2; } }
    const int m0 = blockIdx.y * 128, n0 = blockIdx.x * 128;
    const int wm = w >> 1, wn = w & 1;
    const int row8 = lane >> 3, cch = lane & 7;
    const int gch = cch ^ row8;          // swizzled source chunk index

    f32x4 acc[4][4];
#pragma unroll
    for (int i = 0; i < 4; i++)
#pragma unroll
        for (int j = 0; j < 4; j++) acc[i][j] = (f32x4){0.f, 0.f, 0.f, 0.f};

    for (int k0 = 0; k0 < DIM; k0 += 64) {
        __syncthreads();
#pragma unroll
        for (int j = 0; j < 4; j++) {
            const int r = w * 32 + j * 8;
            gload16(X  + (size_t)(m0 + r + row8) * DIM + k0 + gch * 8, &As[r][0]);
            gload16(Wt + (size_t)(n0 + r + row8) * DIM + k0 + gch * 8, &Bs[r][0]);
        }
        __syncthreads();

        half8 a[4][2], b[4][2];
#pragma unroll
        for (int mt = 0; mt < 4; mt++) {
            int m = wm * 64 + mt * 16 + ln;
#pragma unroll
            for (int ks = 0; ks < 2; ks++) {
                int s = (ks * 4 + quad) ^ (ln & 7);
                a[mt][ks] = *(const half8*)&As[m][s * 8];
            }
        }
#pragma unroll
        for (int nt = 0; nt < 4; nt++) {
            int n = wn * 64 + nt * 16 + ln;
#pragma unroll
            for (int ks = 0; ks < 2; ks++) {
                int s = (ks * 4 + quad) ^ (ln & 7);
                b[nt][ks] = *(const half8*)&Bs[n][s * 8];
            }
        }
#pragma unroll
        for (int ks = 0; ks < 2; ks++)
#pragma unroll
            for (int mt = 0; mt < 4; mt++)
#pragma unroll
                for (int nt = 0; nt < 4; nt++)
                    acc[mt][nt] = __builtin_amdgcn_mfma_f32_16x16x32_f16(
                        a[mt][ks], b[nt][ks], acc[mt][nt], 0, 0, 0);
    }

    // epilogue: C/D 16x16 layout col=ln, row=quad*4+reg
#pragma unroll
    for (int nt = 0; nt < 4; nt++) {
        int col = n0 + wn * 64 + nt * 16 + ln;
        float bv = bias[col];
        int head = col / HDIM, hd = col % HDIM;
        int jc = hd >> 1;                   // pair index; parity of hd == parity of ln
        bool isreal = (ln & 1) == 0;
#pragma unroll
        for (int mt = 0; mt < 4; mt++) {
            int row0 = m0 + wm * 64 + mt * 16 + quad * 4;
            if (QKV && bz == 2) {
                // V^T [head][hd][s]: 4 consecutive s values -> packed 8B store
                half4v p;
#pragma unroll
                for (int r = 0; r < 4; r++) p[r] = (_Float16)(acc[mt][nt][r] + bv);
                *(half4v*)&((_Float16*)outv)[(((size_t)2 * NHEADS + head) * HDIM + hd) * S_LEN + row0] = p;
            } else if (QKV) {
                // q/k with fused RoPE: pair partner lives in lane^1
                float v[4], vp[4];
#pragma unroll
                for (int r = 0; r < 4; r++) v[r] = acc[mt][nt][r] + bv;
#pragma unroll
                for (int r = 0; r < 4; r++) vp[r] = __shfl_xor(v[r], 1);
#pragma unroll
                for (int r = 0; r < 4; r++) {
                    int srow = row0 + r;
                    int pos = (jc < 32) ? (srow >> 6) : (srow & 63);
                    float c  = fc[pos * NPAIR + jc];
                    float sn = fs[pos * NPAIR + jc];
                    float xr = isreal ? v[r] : vp[r];
                    float xi = isreal ? vp[r] : v[r];
                    float rot = isreal ? (xr * c - xi * sn) : (xr * sn + xi * c);
                    float outval = (jc < 16) ? v[r] : rot;
                    ((_Float16*)outv)[(((size_t)bz * NHEADS + head) * S_LEN + srow) * HDIM + hd]
                        = (_Float16)outval;
                }
            } else {
#pragma unroll
                for (int r = 0; r < 4; r++)
                    ((float*)outv)[(size_t)(row0 + r) * DIM + col] = acc[mt][nt][r] + bv;
            }
        }
    }
}

// ---------------- MFMA fp16 flash attention ----------------
// 256 threads / 4 waves; wave-pair p owns KV half p (24 tiles).
//  * K staged via global_load_lds, DOUBLE-buffered: prefetch state lives in the vmcnt
//    counter, not VGPRs (reg-prefetch gets rematerialized at the commit point).
//  * Source-side mod-12 rotation swizzle (LDS stays linear as gload_lds requires):
//    logical chunk (r,cc) stored at physical cc'=(cc+r)%12. Read offset within a row
//    is ksel[(nb+kb)%3] ONLY — the rotation already encodes the kb displacement.
//    (R2's extra +64/+128 here read past the row/buffer end -> NaN. Fixed.)
//  * V LDS eliminated: PV A-frags (half4v, row=ln, k=quad*4+j) read DIRECT from global
//    V^T (L2-resident, 1.2 MB/head; lines fully covered across nb).
//  * ONE barrier per tile: issue K[t+1] DMA at tile top -> QK -> softmax -> PV ->
//    s_waitcnt vmcnt(0) (covered by ~600cy of compute) -> barrier.
__global__ __launch_bounds__(256, 3)
void attn_mfma_kernel(const _Float16* __restrict__ qh, const _Float16* __restrict__ kh,
                      const _Float16* __restrict__ vtg, _Float16* __restrict__ aoh)
{
    __shared__ __align__(16) _Float16 Kb[2][2][64 * 96];   // [pair][buf], 48 KB total

    const int tid  = threadIdx.x;      // 0..255
    const int wid  = tid >> 6;         // 0..3
    const int p    = wid >> 1;         // KV half this wave-pair owns
    const int wp   = wid & 1;          // wave within pair
    const int lane = tid & 63;
    const int ln   = lane & 15;
    const int quad = lane >> 4;
    const int h    = blockIdx.y;
    const int q0   = blockIdx.x * 64;
    const float scale_ = 0.10206207261596577f * 1.4426950408889634f;  // 1/sqrt(96) * log2(e)
    const int NT = (S_LEN / 2) / 64;   // 24 tiles per pair

    // Q fragments for 2 q-blocks (B-operand: col=ln=qrow, k=quad*8+j)
    half8 aq[2][3];
#pragma unroll
    for (int qs = 0; qs < 2; qs++) {
        const _Float16* qrow = qh + (((size_t)h * S_LEN) + q0 + (wp * 2 + qs) * 16 + ln) * HDIM;
#pragma unroll
        for (int kb = 0; kb < 3; kb++) {
            half8 a = *(const half8*)&qrow[kb * 32 + quad * 8];
            half8 v;
#pragma unroll
            for (int i = 0; i < 8; i++) v[i] = (_Float16)((float)a[i] * scale_);
            aq[qs][kb] = v;
        }
    }

    f32x4 o[2][6];
#pragma unroll
    for (int qs = 0; qs < 2; qs++)
#pragma unroll
        for (int dn = 0; dn < 6; dn++) o[qs][dn] = (f32x4){0.f, 0.f, 0.f, 0.f};
    float m_[2] = {-INFINITY, -INFINITY}, l_[2] = {0.f, 0.f};  // l_ per-lane (quad-partial)

    const char* kbase = (const char*)(kh + ((size_t)h * S_LEN + p * (S_LEN / 2)) * HDIM);

    // K staging precompute: wave-inst i covers physical chunks pc = i*128 + (tid&127);
    // physical chunk pc = (row r = pc/12, cc_p = pc%12) holds logical chunk (cc_p - r) mod 12.
    int koffb[6];
#pragma unroll
    for (int i = 0; i < 6; i++) {
        int pc = i * 128 + (tid & 127);
        int r  = pc / 12, c = pc - r * 12;
        int rm = r % 12;
        int cl = c - rm; if (cl < 0) cl += 12;
        koffb[i] = r * 192 + cl * 16;
    }
    // QK read: physical chunk cc' = (quad + ln + 4*(nb+kb)) % 12 = ksel[(nb+kb)%3]
    const int A0 = (quad + ln) % 12;
    int ksel[3];
    ksel[0] = A0 * 16;
    { int t1 = A0 + 4; if (t1 >= 12) t1 -= 12; ksel[1] = t1 * 16; }
    { int t2 = A0 + 8; if (t2 >= 12) t2 -= 12; ksel[2] = t2 * 16; }

    // V direct-read row pointers: V^T row d = dn*16+ln, k-slot quad*4
    const _Float16* vrow[6];
#pragma unroll
    for (int dn = 0; dn < 6; dn++)
        vrow[dn] = vtg + (size_t)h * HDIM * S_LEN + (size_t)(dn * 16 + ln) * S_LEN
                 + p * (S_LEN / 2) + quad * 4;

    // prologue: stage tile 0 into buf 0
#pragma unroll
    for (int i = 0; i < 6; i++)
        gload16(kbase + koffb[i], &Kb[p][0][i * 1024 + wp * 512]);
    asm volatile("s_waitcnt vmcnt(0)");
    __syncthreads();

    for (int kt = 0; kt < NT; ++kt) {
        const int cur = kt & 1;
        // issue next K tile's DMA into the other buffer (drained at loop-end vmcnt)
        if (kt + 1 < NT) {
            const char* ks2 = kbase + (size_t)(kt + 1) * 12288;
#pragma unroll
            for (int i = 0; i < 6; i++)
                gload16(ks2 + koffb[i], &Kb[p][cur ^ 1][i * 1024 + wp * 512]);
            __builtin_amdgcn_sched_barrier(0);
        }

        // S^T = K * Q^T; K-frags read ONCE, used for both q-blocks
        const char* Kc = (const char*)&Kb[p][cur][0];
        f32x4 s[2][4];
#pragma unroll
        for (int nb = 0; nb < 4; nb++) {
            const char* krow = Kc + (nb * 16 + ln) * 192;
            half8 ak0 = *(const half8*)(krow + ksel[(nb + 0) % 3]);
            half8 ak1 = *(const half8*)(krow + ksel[(nb + 1) % 3]);
            half8 ak2 = *(const half8*)(krow + ksel[(nb + 2) % 3]);
#pragma unroll
            for (int qs = 0; qs < 2; qs++) {
                f32x4 acc = (f32x4){0.f, 0.f, 0.f, 0.f};
                acc = __builtin_amdgcn_mfma_f32_16x16x32_f16(ak0, aq[qs][0], acc, 0, 0, 0);
                acc = __builtin_amdgcn_mfma_f32_16x16x32_f16(ak1, aq[qs][1], acc, 0, 0, 0);
                acc = __builtin_amdgcn_mfma_f32_16x16x32_f16(ak2, aq[qs][2], acc, 0, 0, 0);
                s[qs][nb] = acc;
            }
        }

        // online softmax in log2 domain; defer-max skips cross-lane work most tiles
        half4v ap[2][4];
#pragma unroll
        for (int qs = 0; qs < 2; qs++) {
            float ma = fmaxf(fmaxf(s[qs][0][0], s[qs][0][1]), fmaxf(s[qs][0][2], s[qs][0][3]));
            float mb = fmaxf(fmaxf(s[qs][1][0], s[qs][1][1]), fmaxf(s[qs][1][2], s[qs][1][3]));
            float mc = fmaxf(fmaxf(s[qs][2][0], s[qs][2][1]), fmaxf(s[qs][2][2], s[qs][2][3]));
            float md = fmaxf(fmaxf(s[qs][3][0], s[qs][3][1]), fmaxf(s[qs][3][2], s[qs][3][3]));
            float mx = fmaxf(fmaxf(ma, mb), fmaxf(mc, md));
            if (!__all(mx <= m_[qs] + 8.0f)) {       // rescale only when max really grew
                mx = fmaxf(mx, __shfl_xor(mx, 16));
                mx = fmaxf(mx, __shfl_xor(mx, 32));
                float mn = fmaxf(m_[qs], mx);
                float al = __builtin_amdgcn_exp2f(m_[qs] - mn);
                m_[qs] = mn;
                l_[qs] *= al;
#pragma unroll
                for (int dn = 0; dn < 6; dn++)
#pragma unroll
                    for (int r = 0; r < 4; r++) o[qs][dn][r] *= al;
            }
            float rs = 0.f;
            float mq = m_[qs];
#pragma unroll
            for (int nb = 0; nb < 4; nb++) {
                float p0 = __builtin_amdgcn_exp2f(s[qs][nb][0] - mq);
                float p1 = __builtin_amdgcn_exp2f(s[qs][nb][1] - mq);
                float p2 = __builtin_amdgcn_exp2f(s[qs][nb][2] - mq);
                float p3 = __builtin_amdgcn_exp2f(s[qs][nb][3] - mq);
                rs += (p0 + p1) + (p2 + p3);
                half4v pk = { (_Float16)p0, (_Float16)p1, (_Float16)p2, (_Float16)p3 };
                ap[qs][nb] = pk;                      // B-frag of 16x16x16: col=ln, k=quad*4+j
            }
            l_[qs] += rs;                             // cross-quad reduce deferred to epilogue
        }

        // PV with 16x16x16: A = V^T frag straight from global (L2-resident)
#pragma unroll
        for (int nb = 0; nb < 4; nb++) {
#pragma unroll
            for (int dn = 0; dn < 6; dn++) {
                half4v av = *(const half4v*)(vrow[dn] + kt * 64 + nb * 16);
                o[0][dn] = __builtin_amdgcn_mfma_f32_16x16x16f16(av, ap[0][nb], o[0][dn], 0, 0, 0);
                o[1][dn] = __builtin_amdgcn_mfma_f32_16x16x16f16(av, ap[1][nb], o[1][dn], 0, 0, 0);
            }
        }

        asm volatile("s_waitcnt vmcnt(0)");   // next K tile's DMA landed (covered by compute)
        __syncthreads();                      // everyone's DMA committed; K[t] reads all done
    }

    // ---- cross-pair merge through LDS (overlays Kb; all tile work is done) ----
    float lt[2];
#pragma unroll
    for (int qs = 0; qs < 2; qs++) {       // finish the deferred cross-quad l reduction
        float l = l_[qs];
        l += __shfl_xor(l, 16);
        l += __shfl_xor(l, 32);
        lt[qs] = l;
    }
    float*  scr = (float*)&Kb[0][0][0];                      // 64 x 100 f32 (25.6 KB)
    float2* mlb = (float2*)((char*)&Kb[0][0][0] + 26624);    // 64 x {m,l}
    if (p == 1) {
#pragma unroll
        for (int qs = 0; qs < 2; qs++) {
            int row = (wp * 2 + qs) * 16 + ln;
            if (quad == 0) mlb[row] = make_float2(m_[qs], lt[qs]);
#pragma unroll
            for (int dn = 0; dn < 6; dn++)
                *(f32x4*)&scr[row * 100 + dn * 16 + quad * 4] = o[qs][dn];
        }
    }
    __syncthreads();
    if (p == 0) {
#pragma unroll
        for (int qs = 0; qs < 2; qs++) {
            int row = (wp * 2 + qs) * 16 + ln;
            float2 ml1 = mlb[row];
            float mm = fmaxf(m_[qs], ml1.x);
            float a0 = __builtin_amdgcn_exp2f(m_[qs] - mm);
            float a1 = __builtin_amdgcn_exp2f(ml1.x - mm);
            float li = 1.0f / (lt[qs] * a0 + ml1.y * a1);
            const size_t rowbase = (size_t)(q0 + row) * DIM + h * HDIM;
#pragma unroll
            for (int dn = 0; dn < 6; dn++) {
                f32x4 o1 = *(const f32x4*)&scr[row * 100 + dn * 16 + quad * 4];
                half4v pk;
#pragma unroll
                for (int r = 0; r < 4; r++)
                    pk[r] = (_Float16)((o[qs][dn][r] * a0 + o1[r] * a1) * li);
                *(half4v*)&aoh[rowbase + dn * 16 + quad * 4] = pk;
            }
        }
    }
}

extern "C" void kernel_launch(void* const* d_in, const int* in_sizes, int n_in,
                              void* d_out, int out_size, void* d_ws, size_t ws_size,
                              hipStream_t stream) {
    const float* x  = (const float*)d_in[0];
    const float* wq = (const float*)d_in[1];
    const float* bq = (const float*)d_in[2];
    const float* wk = (const float*)d_in[3];
    const float* bk = (const float*)d_in[4];
    const float* wv = (const float*)d_in[5];
    const float* bv = (const float*)d_in[6];
    const float* wo = (const float*)d_in[7];
    const float* bo = (const float*)d_in[8];
    const float* fc = (const float*)d_in[9];
    const float* fs = (const float*)d_in[10];
    float* out = (float*)d_out;

    const size_t per  = (size_t)NHEADS * S_LEN * HDIM;   // 4,718,592
    const size_t dim2 = (size_t)DIM * DIM;               // 2,359,296
    _Float16* hws  = (_Float16*)d_ws;
    _Float16* qkvh = hws;                 // q,k fp16 [head][s][hd] (roped); v fp16 [head][hd][s]
    _Float16* qh   = qkvh;
    _Float16* kh   = qkvh + per;
    _Float16* vth  = qkvh + 2 * per;
    _Float16* xh   = hws + 3 * per;       // x fp16; later reused as ao fp16
    _Float16* wth  = hws + 4 * per;       // 4 transposed weights fp16

    convert_f32_f16<<<(int)((S_LEN * DIM / 4 + 255) / 256), 256, 0, stream>>>(
        x, xh, S_LEN * DIM / 4);
    transpose_w<<<dim3(DIM / 64, DIM / 64, 4), 256, 0, stream>>>(wq, wk, wv, wo, wth);

    // fused QKV projection + RoPE -> fp16
    gemm_f16<true><<<dim3(DIM / 128, S_LEN / 128, 3), 256, 0, stream>>>(
        xh, wth, wth + dim2, wth + 2 * dim2, bq, bk, bv, fc, fs, qkvh);
    attn_mfma_kernel<<<dim3(S_LEN / 64, NHEADS), 256, 0, stream>>>(qh, kh, vth, xh);
    gemm_f16<false><<<dim3(DIM / 128, S_LEN / 128, 1), 256, 0, stream>>>(
        xh, wth + 3 * dim2, nullptr, nullptr, bo, nullptr, nullptr, fc, fs, out);
}

// Round 4
// 333.252 us; speedup vs baseline: 1.3278x; 1.3278x over previous
//
#include <hip/hip_runtime.h>
#include <math.h>

#define S_LEN 3072
#define DIM 1536
#define NHEADS 16
#define HDIM 96
#define NPAIR 48

typedef __attribute__((ext_vector_type(8))) _Float16 half8;
typedef __attribute__((ext_vector_type(4))) _Float16 half4v;
typedef __attribute__((ext_vector_type(2))) _Float16 half2v;
typedef __attribute__((ext_vector_type(4))) float f32x4;

__device__ inline void gload16(const void* g, void* l) {
    __builtin_amdgcn_global_load_lds(
        (const __attribute__((address_space(1))) void*)g,
        (__attribute__((address_space(3))) void*)l, 16, 0, 0);
}

// Pinned 16B global load: volatile asm cannot be sunk/rematerialized by the
// compiler (R1: plain-load prefetch was re-issued at the commit point; R3:
// direct PV loads were never hoisted -> latency-exposed). NOTE: the compiler
// does NOT track this load for waitcnt purposes — consumer must issue an
// explicit `s_waitcnt vmcnt(0)` before reading the result.
__device__ inline uint4 gld128(const _Float16* p) {
    uint4 r;
    asm volatile("global_load_dwordx4 %0, %1, off"
                 : "=v"(r) : "v"(p));
    return r;
}

// ---------------- prep: fp32 -> fp16 elementwise ----------------
__global__ __launch_bounds__(256)
void convert_f32_f16(const float* __restrict__ src, _Float16* __restrict__ dst, int n4)
{
    int i = blockIdx.x * 256 + threadIdx.x;
    if (i < n4) {
        float4 v = *(const float4*)&src[(size_t)i * 4];
        half4v h = { (_Float16)v.x, (_Float16)v.y, (_Float16)v.z, (_Float16)v.w };
        *(half4v*)&dst[(size_t)i * 4] = h;
    }
}

// ---------------- prep: W[k][n] fp32 -> Wt[n][k] fp16 (64x64 LDS tiles) ----------------
__global__ __launch_bounds__(256)
void transpose_w(const float* __restrict__ w0, const float* __restrict__ w1,
                 const float* __restrict__ w2, const float* __restrict__ w3,
                 _Float16* __restrict__ wt)
{
    __shared__ _Float16 t[64][68];
    const int z = blockIdx.z;
    const float* W = (z == 0) ? w0 : (z == 1) ? w1 : (z == 2) ? w2 : w3;
    _Float16* O = wt + (size_t)z * DIM * DIM;
    const int k0 = blockIdx.y * 64, n0 = blockIdx.x * 64;
    const int tid = threadIdx.x;
    const int r = tid >> 4, c4 = (tid & 15) * 4;
#pragma unroll
    for (int g = 0; g < 4; g++) {
        int kk = r + g * 16;
        float4 v = *(const float4*)&W[(size_t)(k0 + kk) * DIM + n0 + c4];
        t[c4 + 0][kk] = (_Float16)v.x; t[c4 + 1][kk] = (_Float16)v.y;
        t[c4 + 2][kk] = (_Float16)v.z; t[c4 + 3][kk] = (_Float16)v.w;
    }
    __syncthreads();
    const int nr = tid >> 2, ks = (tid & 3) * 16;
#pragma unroll
    for (int s = 0; s < 4; s++)
        *(ushort4*)&O[(size_t)(n0 + nr) * DIM + k0 + ks + s * 4] =
            *(ushort4*)&t[nr][ks + s * 4];
}

// ---------------- fp16 MFMA GEMM with fused RoPE epilogue ----------------
// QKV=true: q,k written [head][s][hd] with RoPE applied; v written TRANSPOSED [head][hd][s].
template<bool QKV>
__global__ __launch_bounds__(256)
void gemm_f16(const _Float16* __restrict__ X,
              const _Float16* __restrict__ W0t, const _Float16* __restrict__ W1t,
              const _Float16* __restrict__ W2t,
              const float* __restrict__ B0, const float* __restrict__ B1,
              const float* __restrict__ B2,
              const float* __restrict__ fc, const float* __restrict__ fs,
              void* __restrict__ outv)
{
    __shared__ __align__(16) _Float16 As[128][64];   // 16 KB
    __shared__ __align__(16) _Float16 Bs[128][64];   // 16 KB

    const int tid = threadIdx.x;
    const int w = tid >> 6, lane = tid & 63;
    const int ln = lane & 15, quad = lane >> 4;
    const int bz = blockIdx.z;
    const _Float16* Wt = W0t; const float* bias = B0;
    if (QKV) { if (bz == 1) { Wt = W1t; bias = B1; } else if (bz == 2) { Wt = W2t; bias = B2; } }
    const int m0 = blockIdx.y * 128, n0 = blockIdx.x * 128;
    const int wm = w >> 1, wn = w & 1;
    const int row8 = lane >> 3, cch = lane & 7;
    const int gch = cch ^ row8;          // swizzled source chunk index

    f32x4 acc[4][4];
#pragma unroll
    for (int i = 0; i < 4; i++)
#pragma unroll
        for (int j = 0; j < 4; j++) acc[i][j] = (f32x4){0.f, 0.f, 0.f, 0.f};

    for (int k0 = 0; k0 < DIM; k0 += 64) {
        __syncthreads();
#pragma unroll
        for (int j = 0; j < 4; j++) {
            const int r = w * 32 + j * 8;
            gload16(X  + (size_t)(m0 + r + row8) * DIM + k0 + gch * 8, &As[r][0]);
            gload16(Wt + (size_t)(n0 + r + row8) * DIM + k0 + gch * 8, &Bs[r][0]);
        }
        __syncthreads();

        half8 a[4][2], b[4][2];
#pragma unroll
        for (int mt = 0; mt < 4; mt++) {
            int m = wm * 64 + mt * 16 + ln;
#pragma unroll
            for (int ks = 0; ks < 2; ks++) {
                int s = (ks * 4 + quad) ^ (ln & 7);
                a[mt][ks] = *(const half8*)&As[m][s * 8];
            }
        }
#pragma unroll
        for (int nt = 0; nt < 4; nt++) {
            int n = wn * 64 + nt * 16 + ln;
#pragma unroll
            for (int ks = 0; ks < 2; ks++) {
                int s = (ks * 4 + quad) ^ (ln & 7);
                b[nt][ks] = *(const half8*)&Bs[n][s * 8];
            }
        }
#pragma unroll
        for (int ks = 0; ks < 2; ks++)
#pragma unroll
            for (int mt = 0; mt < 4; mt++)
#pragma unroll
                for (int nt = 0; nt < 4; nt++)
                    acc[mt][nt] = __builtin_amdgcn_mfma_f32_16x16x32_f16(
                        a[mt][ks], b[nt][ks], acc[mt][nt], 0, 0, 0);
    }

    // epilogue: C/D 16x16 layout col=ln, row=quad*4+reg
#pragma unroll
    for (int nt = 0; nt < 4; nt++) {
        int col = n0 + wn * 64 + nt * 16 + ln;
        float bv = bias[col];
        int head = col / HDIM, hd = col % HDIM;
        int jc = hd >> 1;                   // pair index; parity of hd == parity of ln
        bool isreal = (ln & 1) == 0;
#pragma unroll
        for (int mt = 0; mt < 4; mt++) {
            int row0 = m0 + wm * 64 + mt * 16 + quad * 4;
            if (QKV && bz == 2) {
                // V^T [head][hd][s]: 4 consecutive s values -> packed 8B store
                half4v p;
#pragma unroll
                for (int r = 0; r < 4; r++) p[r] = (_Float16)(acc[mt][nt][r] + bv);
                *(half4v*)&((_Float16*)outv)[(((size_t)2 * NHEADS + head) * HDIM + hd) * S_LEN + row0] = p;
            } else if (QKV) {
                // q/k with fused RoPE: pair partner lives in lane^1
                float v[4], vp[4];
#pragma unroll
                for (int r = 0; r < 4; r++) v[r] = acc[mt][nt][r] + bv;
#pragma unroll
                for (int r = 0; r < 4; r++) vp[r] = __shfl_xor(v[r], 1);
#pragma unroll
                for (int r = 0; r < 4; r++) {
                    int srow = row0 + r;
                    int pos = (jc < 32) ? (srow >> 6) : (srow & 63);
                    float c  = fc[pos * NPAIR + jc];
                    float sn = fs[pos * NPAIR + jc];
                    float xr = isreal ? v[r] : vp[r];
                    float xi = isreal ? vp[r] : v[r];
                    float rot = isreal ? (xr * c - xi * sn) : (xr * sn + xi * c);
                    float outval = (jc < 16) ? v[r] : rot;
                    ((_Float16*)outv)[(((size_t)bz * NHEADS + head) * S_LEN + srow) * HDIM + hd]
                        = (_Float16)outval;
                }
            } else {
#pragma unroll
                for (int r = 0; r < 4; r++)
                    ((float*)outv)[(size_t)(row0 + r) * DIM + col] = acc[mt][nt][r] + bv;
            }
        }
    }
}

// ---------------- MFMA fp16 flash attention ----------------
// 256 threads / 4 waves; wave-pair p owns KV half p (24 tiles).
//  * K: global_load_lds DOUBLE-buffered + mod-12 rotation swizzle (R3, proven).
//    Prefetch lives in the vmcnt counter -> unsinkable, zero VGPR.
//  * V: staged to LDS (Vt[96][72] XOR layout, R1-proven) through PINNED asm
//    global_load_dwordx4 named scalars. volatile asm can't be rematerialized or
//    sunk (R1's plain-load prefetch was re-issued at commit; R3's direct PV
//    global reads were latency-exposed, 24 serialized L2 hits/tile -> 235us).
//    Loads issue at tile top; latency covered by QK+softmax+PV; committed after
//    the reads-done barrier behind an explicit vmcnt(0) (compiler doesn't track
//    asm loads, so __syncthreads' auto-drain does NOT cover them).
//  * Two barriers/tile, neither hiding global latency:
//      issue K-DMA + V-asm -> QK -> softmax -> PV -> [B] -> vmcnt(0) ->
//      commit V -> [A] -> next tile.
__global__ __launch_bounds__(256, 2)
void attn_mfma_kernel(const _Float16* __restrict__ qh, const _Float16* __restrict__ kh,
                      const _Float16* __restrict__ vtg, _Float16* __restrict__ aoh)
{
    __shared__ __align__(16) _Float16 Kb[2][2][64 * 96];   // [pair][buf], 48 KB
    __shared__ __align__(16) _Float16 Vt[2][96][72];       // [pair], 27 KB, XOR chunks

    const int tid  = threadIdx.x;      // 0..255
    const int wid  = tid >> 6;         // 0..3
    const int p    = wid >> 1;         // KV half this wave-pair owns
    const int wp   = wid & 1;          // wave within pair
    const int lane = tid & 63;
    const int ln   = lane & 15;
    const int quad = lane >> 4;
    const int h    = blockIdx.y;
    const int q0   = blockIdx.x * 64;
    const float scale_ = 0.10206207261596577f * 1.4426950408889634f;  // 1/sqrt(96) * log2(e)
    const int NT = (S_LEN / 2) / 64;   // 24 tiles per pair

    // Q fragments for 2 q-blocks (B-operand: col=ln=qrow, k=quad*8+j)
    half8 aq[2][3];
#pragma unroll
    for (int qs = 0; qs < 2; qs++) {
        const _Float16* qrow = qh + (((size_t)h * S_LEN) + q0 + (wp * 2 + qs) * 16 + ln) * HDIM;
#pragma unroll
        for (int kb = 0; kb < 3; kb++) {
            half8 a = *(const half8*)&qrow[kb * 32 + quad * 8];
            half8 v;
#pragma unroll
            for (int i = 0; i < 8; i++) v[i] = (_Float16)((float)a[i] * scale_);
            aq[qs][kb] = v;
        }
    }

    f32x4 o[2][6];
#pragma unroll
    for (int qs = 0; qs < 2; qs++)
#pragma unroll
        for (int dn = 0; dn < 6; dn++) o[qs][dn] = (f32x4){0.f, 0.f, 0.f, 0.f};
    float m_[2] = {-INFINITY, -INFINITY}, l_[2] = {0.f, 0.f};  // l_ per-lane (quad-partial)

    const char* kbase = (const char*)(kh + ((size_t)h * S_LEN + p * (S_LEN / 2)) * HDIM);

    // K staging precompute: wave-inst i covers physical chunks pc = i*128 + (tid&127);
    // physical chunk pc = (row r = pc/12, cc_p = pc%12) holds logical chunk (cc_p - r) mod 12.
    int koffb[6];
#pragma unroll
    for (int i = 0; i < 6; i++) {
        int pc = i * 128 + (tid & 127);
        int r  = pc / 12, c = pc - r * 12;
        int rm = r % 12;
        int cl = c - rm; if (cl < 0) cl += 12;
        koffb[i] = r * 192 + cl * 16;
    }
    // QK read: physical chunk cc' = (quad + ln + 4*(nb+kb)) % 12 = ksel[(nb+kb)%3]
    const int A0 = (quad + ln) % 12;
    int ksel[3];
    ksel[0] = A0 * 16;
    { int t1 = A0 + 4; if (t1 >= 12) t1 -= 12; ksel[1] = t1 * 16; }
    { int t2 = A0 + 8; if (t2 >= 12) t2 -= 12; ksel[2] = t2 * 16; }

    // V staging: pair-local thread tp -> d rows (tp>>3)+16u, chunk vc=tp&7;
    // XOR slot = vc ^ (vd0&7)
    const int tp = tid & 127;
    const int vd0 = tp >> 3, vc = tp & 7;
    const _Float16* vsrc0 = vtg + (size_t)h * HDIM * S_LEN + (size_t)vd0 * S_LEN
                          + p * (S_LEN / 2) + vc * 8;
    _Float16* vdst = &Vt[p][vd0][(vc ^ (vd0 & 7)) * 8];

    // ---- prologue: stage tile 0 (K via DMA, V via pinned regs) ----
#pragma unroll
    for (int i = 0; i < 6; i++)
        gload16(kbase + koffb[i], &Kb[p][0][i * 1024 + wp * 512]);
    uint4 vp0, vp1, vp2, vp3, vp4, vp5;
    vp0 = gld128(vsrc0 + 0 * 16 * S_LEN);
    vp1 = gld128(vsrc0 + 1 * 16 * S_LEN);
    vp2 = gld128(vsrc0 + 2 * 16 * S_LEN);
    vp3 = gld128(vsrc0 + 3 * 16 * S_LEN);
    vp4 = gld128(vsrc0 + 4 * 16 * S_LEN);
    vp5 = gld128(vsrc0 + 5 * 16 * S_LEN);
    asm volatile("s_waitcnt vmcnt(0)" ::: "memory");
    __builtin_amdgcn_sched_barrier(0);
    *(uint4*)(vdst + 0 * 16 * 72) = vp0;  *(uint4*)(vdst + 1 * 16 * 72) = vp1;
    *(uint4*)(vdst + 2 * 16 * 72) = vp2;  *(uint4*)(vdst + 3 * 16 * 72) = vp3;
    *(uint4*)(vdst + 4 * 16 * 72) = vp4;  *(uint4*)(vdst + 5 * 16 * 72) = vp5;
    __syncthreads();

    for (int kt = 0; kt < NT; ++kt) {
        const int cur = kt & 1;
        // issue next tile's K DMA (other buffer) and V pinned loads
        if (kt + 1 < NT) {
            const char* ks2 = kbase + (size_t)(kt + 1) * 12288;
#pragma unroll
            for (int i = 0; i < 6; i++)
                gload16(ks2 + koffb[i], &Kb[p][cur ^ 1][i * 1024 + wp * 512]);
            const _Float16* vs2 = vsrc0 + (kt + 1) * 64;
            vp0 = gld128(vs2 + 0 * 16 * S_LEN);
            vp1 = gld128(vs2 + 1 * 16 * S_LEN);
            vp2 = gld128(vs2 + 2 * 16 * S_LEN);
            vp3 = gld128(vs2 + 3 * 16 * S_LEN);
            vp4 = gld128(vs2 + 4 * 16 * S_LEN);
            vp5 = gld128(vs2 + 5 * 16 * S_LEN);
            __builtin_amdgcn_sched_barrier(0);
        }

        // S^T = K * Q^T; K-frags read ONCE, used for both q-blocks
        const char* Kc = (const char*)&Kb[p][cur][0];
        f32x4 s[2][4];
#pragma unroll
        for (int nb = 0; nb < 4; nb++) {
            const char* krow = Kc + (nb * 16 + ln) * 192;
            half8 ak0 = *(const half8*)(krow + ksel[(nb + 0) % 3]);
            half8 ak1 = *(const half8*)(krow + ksel[(nb + 1) % 3]);
            half8 ak2 = *(const half8*)(krow + ksel[(nb + 2) % 3]);
#pragma unroll
            for (int qs = 0; qs < 2; qs++) {
                f32x4 acc = (f32x4){0.f, 0.f, 0.f, 0.f};
                acc = __builtin_amdgcn_mfma_f32_16x16x32_f16(ak0, aq[qs][0], acc, 0, 0, 0);
                acc = __builtin_amdgcn_mfma_f32_16x16x32_f16(ak1, aq[qs][1], acc, 0, 0, 0);
                acc = __builtin_amdgcn_mfma_f32_16x16x32_f16(ak2, aq[qs][2], acc, 0, 0, 0);
                s[qs][nb] = acc;
            }
        }

        // online softmax in log2 domain; defer-max skips cross-lane work most tiles
        half4v ap[2][4];
#pragma unroll
        for (int qs = 0; qs < 2; qs++) {
            float ma = fmaxf(fmaxf(s[qs][0][0], s[qs][0][1]), fmaxf(s[qs][0][2], s[qs][0][3]));
            float mb = fmaxf(fmaxf(s[qs][1][0], s[qs][1][1]), fmaxf(s[qs][1][2], s[qs][1][3]));
            float mc = fmaxf(fmaxf(s[qs][2][0], s[qs][2][1]), fmaxf(s[qs][2][2], s[qs][2][3]));
            float md = fmaxf(fmaxf(s[qs][3][0], s[qs][3][1]), fmaxf(s[qs][3][2], s[qs][3][3]));
            float mx = fmaxf(fmaxf(ma, mb), fmaxf(mc, md));
            if (!__all(mx <= m_[qs] + 8.0f)) {       // rescale only when max really grew
                mx = fmaxf(mx, __shfl_xor(mx, 16));
                mx = fmaxf(mx, __shfl_xor(mx, 32));
                float mn = fmaxf(m_[qs], mx);
                float al = __builtin_amdgcn_exp2f(m_[qs] - mn);
                m_[qs] = mn;
                l_[qs] *= al;
#pragma unroll
                for (int dn = 0; dn < 6; dn++)
#pragma unroll
                    for (int r = 0; r < 4; r++) o[qs][dn][r] *= al;
            }
            float rs = 0.f;
            float mq = m_[qs];
#pragma unroll
            for (int nb = 0; nb < 4; nb++) {
                float p0 = __builtin_amdgcn_exp2f(s[qs][nb][0] - mq);
                float p1 = __builtin_amdgcn_exp2f(s[qs][nb][1] - mq);
                float p2 = __builtin_amdgcn_exp2f(s[qs][nb][2] - mq);
                float p3 = __builtin_amdgcn_exp2f(s[qs][nb][3] - mq);
                rs += (p0 + p1) + (p2 + p3);
                half4v pk = { (_Float16)p0, (_Float16)p1, (_Float16)p2, (_Float16)p3 };
                ap[qs][nb] = pk;                      // B-frag of 16x16x16: col=ln, k=quad*4+j
            }
            l_[qs] += rs;                             // cross-quad reduce deferred to epilogue
        }

        // PV with 16x16x16: A = V^T frag from LDS (XOR chunk layout)
#pragma unroll
        for (int nb = 0; nb < 4; nb++) {
            const int off = (((nb * 2 + (quad >> 1)) ^ (ln & 7)) * 8) + (quad & 1) * 4;
#pragma unroll
            for (int dn = 0; dn < 6; dn++) {
                half4v av = *(const half4v*)&Vt[p][dn * 16 + ln][off];
                o[0][dn] = __builtin_amdgcn_mfma_f32_16x16x16f16(av, ap[0][nb], o[0][dn], 0, 0, 0);
                o[1][dn] = __builtin_amdgcn_mfma_f32_16x16x16f16(av, ap[1][nb], o[1][dn], 0, 0, 0);
            }
        }

        __syncthreads();   // B: all PV reads of Vt done; K[t+1] DMA drained (tracked)
        asm volatile("s_waitcnt vmcnt(0)" ::: "memory");  // V[t+1] pinned regs arrived
        __builtin_amdgcn_sched_barrier(0);
        if (kt + 1 < NT) {
            *(uint4*)(vdst + 0 * 16 * 72) = vp0;  *(uint4*)(vdst + 1 * 16 * 72) = vp1;
            *(uint4*)(vdst + 2 * 16 * 72) = vp2;  *(uint4*)(vdst + 3 * 16 * 72) = vp3;
            *(uint4*)(vdst + 4 * 16 * 72) = vp4;  *(uint4*)(vdst + 5 * 16 * 72) = vp5;
        }
        __syncthreads();   // A: V[t+1] visible to pair partner
    }

    // ---- cross-pair merge through LDS (overlays Kb; all tile work is done) ----
    float lt[2];
#pragma unroll
    for (int qs = 0; qs < 2; qs++) {       // finish the deferred cross-quad l reduction
        float l = l_[qs];
        l += __shfl_xor(l, 16);
        l += __shfl_xor(l, 32);
        lt[qs] = l;
    }
    float*  scr = (float*)&Kb[0][0][0];                      // 64 x 100 f32 (25.6 KB)
    float2* mlb = (float2*)((char*)&Kb[0][0][0] + 26624);    // 64 x {m,l}
    if (p == 1) {
#pragma unroll
        for (int qs = 0; qs < 2; qs++) {
            int row = (wp * 2 + qs) * 16 + ln;
            if (quad == 0) mlb[row] = make_float2(m_[qs], lt[qs]);
#pragma unroll
            for (int dn = 0; dn < 6; dn++)
                *(f32x4*)&scr[row * 100 + dn * 16 + quad * 4] = o[qs][dn];
        }
    }
    __syncthreads();
    if (p == 0) {
#pragma unroll
        for (int qs = 0; qs < 2; qs++) {
            int row = (wp * 2 + qs) * 16 + ln;
            float2 ml1 = mlb[row];
            float mm = fmaxf(m_[qs], ml1.x);
            float a0 = __builtin_amdgcn_exp2f(m_[qs] - mm);
            float a1 = __builtin_amdgcn_exp2f(ml1.x - mm);
            float li = 1.0f / (lt[qs] * a0 + ml1.y * a1);
            const size_t rowbase = (size_t)(q0 + row) * DIM + h * HDIM;
#pragma unroll
            for (int dn = 0; dn < 6; dn++) {
                f32x4 o1 = *(const f32x4*)&scr[row * 100 + dn * 16 + quad * 4];
                half4v pk;
#pragma unroll
                for (int r = 0; r < 4; r++)
                    pk[r] = (_Float16)((o[qs][dn][r] * a0 + o1[r] * a1) * li);
                *(half4v*)&aoh[rowbase + dn * 16 + quad * 4] = pk;
            }
        }
    }
}

extern "C" void kernel_launch(void* const* d_in, const int* in_sizes, int n_in,
                              void* d_out, int out_size, void* d_ws, size_t ws_size,
                              hipStream_t stream) {
    const float* x  = (const float*)d_in[0];
    const float* wq = (const float*)d_in[1];
    const float* bq = (const float*)d_in[2];
    const float* wk = (const float*)d_in[3];
    const float* bk = (const float*)d_in[4];
    const float* wv = (const float*)d_in[5];
    const float* bv = (const float*)d_in[6];
    const float* wo = (const float*)d_in[7];
    const float* bo = (const float*)d_in[8];
    const float* fc = (const float*)d_in[9];
    const float* fs = (const float*)d_in[10];
    float* out = (float*)d_out;

    const size_t per  = (size_t)NHEADS * S_LEN * HDIM;   // 4,718,592
    const size_t dim2 = (size_t)DIM * DIM;               // 2,359,296
    _Float16* hws  = (_Float16*)d_ws;
    _Float16* qkvh = hws;                 // q,k fp16 [head][s][hd] (roped); v fp16 [head][hd][s]
    _Float16* qh   = qkvh;
    _Float16* kh   = qkvh + per;
    _Float16* vth  = qkvh + 2 * per;
    _Float16* xh   = hws + 3 * per;       // x fp16; later reused as ao fp16
    _Float16* wth  = hws + 4 * per;       // 4 transposed weights fp16

    convert_f32_f16<<<(int)((S_LEN * DIM / 4 + 255) / 256), 256, 0, stream>>>(
        x, xh, S_LEN * DIM / 4);
    transpose_w<<<dim3(DIM / 64, DIM / 64, 4), 256, 0, stream>>>(wq, wk, wv, wo, wth);

    // fused QKV projection + RoPE -> fp16
    gemm_f16<true><<<dim3(DIM / 128, S_LEN / 128, 3), 256, 0, stream>>>(
        xh, wth, wth + dim2, wth + 2 * dim2, bq, bk, bv, fc, fs, qkvh);
    attn_mfma_kernel<<<dim3(S_LEN / 64, NHEADS), 256, 0, stream>>>(qh, kh, vth, xh);
    gemm_f16<false><<<dim3(DIM / 128, S_LEN / 128, 1), 256, 0, stream>>>(
        xh, wth + 3 * dim2, nullptr, nullptr, bo, nullptr, nullptr, fc, fs, out);
}

// Round 6
// 330.469 us; speedup vs baseline: 1.3390x; 1.0084x over previous
//
#include <hip/hip_runtime.h>
#include <math.h>

#define S_LEN 3072
#define DIM 1536
#define NHEADS 16
#define HDIM 96
#define NPAIR 48

typedef __attribute__((ext_vector_type(8))) _Float16 half8;
typedef __attribute__((ext_vector_type(4))) _Float16 half4v;
typedef __attribute__((ext_vector_type(2))) _Float16 half2v;
typedef __attribute__((ext_vector_type(4))) float f32x4;
typedef __attribute__((ext_vector_type(16))) float f32x16;

__device__ inline void gload16(const void* g, void* l) {
    __builtin_amdgcn_global_load_lds(
        (const __attribute__((address_space(1))) void*)g,
        (__attribute__((address_space(3))) void*)l, 16, 0, 0);
}

// Pinned 16B global load: volatile asm can't be sunk/rematerialized (R1/R3
// showed the compiler re-issues plain-load "prefetches" at their use point).
// Consumer must issue an explicit `s_waitcnt vmcnt(0)` (untracked by compiler).
__device__ inline uint4 gld128(const _Float16* p) {
    uint4 r;
    asm volatile("global_load_dwordx4 %0, %1, off"
                 : "=v"(r) : "v"(p));
    return r;
}

// ---------------- prep: fp32 -> fp16 elementwise ----------------
__global__ __launch_bounds__(256)
void convert_f32_f16(const float* __restrict__ src, _Float16* __restrict__ dst, int n4)
{
    int i = blockIdx.x * 256 + threadIdx.x;
    if (i < n4) {
        float4 v = *(const float4*)&src[(size_t)i * 4];
        half4v h = { (_Float16)v.x, (_Float16)v.y, (_Float16)v.z, (_Float16)v.w };
        *(half4v*)&dst[(size_t)i * 4] = h;
    }
}

// ---------------- prep: W[k][n] fp32 -> Wt[n][k] fp16 (64x64 LDS tiles) ----------------
__global__ __launch_bounds__(256)
void transpose_w(const float* __restrict__ w0, const float* __restrict__ w1,
                 const float* __restrict__ w2, const float* __restrict__ w3,
                 _Float16* __restrict__ wt)
{
    __shared__ _Float16 t[64][68];
    const int z = blockIdx.z;
    const float* W = (z == 0) ? w0 : (z == 1) ? w1 : (z == 2) ? w2 : w3;
    _Float16* O = wt + (size_t)z * DIM * DIM;
    const int k0 = blockIdx.y * 64, n0 = blockIdx.x * 64;
    const int tid = threadIdx.x;
    const int r = tid >> 4, c4 = (tid & 15) * 4;
#pragma unroll
    for (int g = 0; g < 4; g++) {
        int kk = r + g * 16;
        float4 v = *(const float4*)&W[(size_t)(k0 + kk) * DIM + n0 + c4];
        t[c4 + 0][kk] = (_Float16)v.x; t[c4 + 1][kk] = (_Float16)v.y;
        t[c4 + 2][kk] = (_Float16)v.z; t[c4 + 3][kk] = (_Float16)v.w;
    }
    __syncthreads();
    const int nr = tid >> 2, ks = (tid & 3) * 16;
#pragma unroll
    for (int s = 0; s < 4; s++)
        *(ushort4*)&O[(size_t)(n0 + nr) * DIM + k0 + ks + s * 4] =
            *(ushort4*)&t[nr][ks + s * 4];
}

// ---------------- fp16 MFMA GEMM with fused RoPE epilogue ----------------
// QKV=true: q,k written [head][s][hd] with RoPE applied; v written TRANSPOSED [head][hd][s].
template<bool QKV>
__global__ __launch_bounds__(256)
void gemm_f16(const _Float16* __restrict__ X,
              const _Float16* __restrict__ W0t, const _Float16* __restrict__ W1t,
              const _Float16* __restrict__ W2t,
              const float* __restrict__ B0, const float* __restrict__ B1,
              const float* __restrict__ B2,
              const float* __restrict__ fc, const float* __restrict__ fs,
              void* __restrict__ outv)
{
    __shared__ __align__(16) _Float16 As[128][64];   // 16 KB
    __shared__ __align__(16) _Float16 Bs[128][64];   // 16 KB

    const int tid = threadIdx.x;
    const int w = tid >> 6, lane = tid & 63;
    const int ln = lane & 15, quad = lane >> 4;
    const int bz = blockIdx.z;
    const _Float16* Wt = W0t; const float* bias = B0;
    if (QKV) { if (bz == 1) { Wt = W1t; bias = B1; } else if (bz == 2) { Wt = W2t; bias = B2; } }
    const int m0 = blockIdx.y * 128, n0 = blockIdx.x * 128;
    const int wm = w >> 1, wn = w & 1;
    const int row8 = lane >> 3, cch = lane & 7;
    const int gch = cch ^ row8;          // swizzled source chunk index

    f32x4 acc[4][4];
#pragma unroll
    for (int i = 0; i < 4; i++)
#pragma unroll
        for (int j = 0; j < 4; j++) acc[i][j] = (f32x4){0.f, 0.f, 0.f, 0.f};

    for (int k0 = 0; k0 < DIM; k0 += 64) {
        __syncthreads();
#pragma unroll
        for (int j = 0; j < 4; j++) {
            const int r = w * 32 + j * 8;
            gload16(X  + (size_t)(m0 + r + row8) * DIM + k0 + gch * 8, &As[r][0]);
            gload16(Wt + (size_t)(n0 + r + row8) * DIM + k0 + gch * 8, &Bs[r][0]);
        }
        __syncthreads();

        half8 a[4][2], b[4][2];
#pragma unroll
        for (int mt = 0; mt < 4; mt++) {
            int m = wm * 64 + mt * 16 + ln;
#pragma unroll
            for (int ks = 0; ks < 2; ks++) {
                int s = (ks * 4 + quad) ^ (ln & 7);
                a[mt][ks] = *(const half8*)&As[m][s * 8];
            }
        }
#pragma unroll
        for (int nt = 0; nt < 4; nt++) {
            int n = wn * 64 + nt * 16 + ln;
#pragma unroll
            for (int ks = 0; ks < 2; ks++) {
                int s = (ks * 4 + quad) ^ (ln & 7);
                b[nt][ks] = *(const half8*)&Bs[n][s * 8];
            }
        }
#pragma unroll
        for (int ks = 0; ks < 2; ks++)
#pragma unroll
            for (int mt = 0; mt < 4; mt++)
#pragma unroll
                for (int nt = 0; nt < 4; nt++)
                    acc[mt][nt] = __builtin_amdgcn_mfma_f32_16x16x32_f16(
                        a[mt][ks], b[nt][ks], acc[mt][nt], 0, 0, 0);
    }

    // epilogue: C/D 16x16 layout col=ln, row=quad*4+reg
#pragma unroll
    for (int nt = 0; nt < 4; nt++) {
        int col = n0 + wn * 64 + nt * 16 + ln;
        float bv = bias[col];
        int head = col / HDIM, hd = col % HDIM;
        int jc = hd >> 1;                   // pair index; parity of hd == parity of ln
        bool isreal = (ln & 1) == 0;
#pragma unroll
        for (int mt = 0; mt < 4; mt++) {
            int row0 = m0 + wm * 64 + mt * 16 + quad * 4;
            if (QKV && bz == 2) {
                // V^T [head][hd][s]: 4 consecutive s values -> packed 8B store
                half4v p;
#pragma unroll
                for (int r = 0; r < 4; r++) p[r] = (_Float16)(acc[mt][nt][r] + bv);
                *(half4v*)&((_Float16*)outv)[(((size_t)2 * NHEADS + head) * HDIM + hd) * S_LEN + row0] = p;
            } else if (QKV) {
                // q/k with fused RoPE: pair partner lives in lane^1
                float v[4], vp[4];
#pragma unroll
                for (int r = 0; r < 4; r++) v[r] = acc[mt][nt][r] + bv;
#pragma unroll
                for (int r = 0; r < 4; r++) vp[r] = __shfl_xor(v[r], 1);
#pragma unroll
                for (int r = 0; r < 4; r++) {
                    int srow = row0 + r;
                    int pos = (jc < 32) ? (srow >> 6) : (srow & 63);
                    float c  = fc[pos * NPAIR + jc];
                    float sn = fs[pos * NPAIR + jc];
                    float xr = isreal ? v[r] : vp[r];
                    float xi = isreal ? vp[r] : v[r];
                    float rot = isreal ? (xr * c - xi * sn) : (xr * sn + xi * c);
                    float outval = (jc < 16) ? v[r] : rot;
                    ((_Float16*)outv)[(((size_t)bz * NHEADS + head) * S_LEN + srow) * HDIM + hd]
                        = (_Float16)outval;
                }
            } else {
#pragma unroll
                for (int r = 0; r < 4; r++)
                    ((float*)outv)[(size_t)(row0 + r) * DIM + col] = acc[mt][nt][r] + bv;
            }
        }
    }
}

// ---------------- MFMA fp16 flash attention, 32x32 shapes ----------------
// 256 threads / 4 waves; wave-pair p owns KV half p (24 tiles of 64 kv).
// Wave handles 32 q-rows as the 32 COLUMNS of 32x32 MFMAs (both old q-blocks fused):
//  * QK: S^T[kv32][q32] via 12x mfma_f32_32x32x16_f16 (2 kv-blocks x 6 hd-chunks).
//    A=K frag: row=l&31 (kv), k=(l>>5)*8+j (hd) -> one ds_read_b128 per (row,chunk)
//    against the proven mod-12 rotation layout (conflict-optimal: 8 consecutive
//    rows hit 8 distinct bank granules).
//  * PV: 24x mfma_f32_32x32x8f16. KEY: the 32x32x8 B-frag k-subset (4*hi+j per
//    8-kv block) is EXACTLY the kv subset each lane already holds from the QK
//    C-layout (kv = (reg&3)+8*(reg>>2)+4*hi) -> P stays in-lane, zero exchange.
//  * V: R0-proven Vt[96][64] chunk-XOR layout (phys chunk = c ^ (row&7)),
//    staged via pinned-asm loads (R4-proven), conflict-optimal 8B reads.
//  * K: global_load_lds double-buffer (prefetch lives in vmcnt, unsinkable).
//  * Softmax: column lives in lanes (l, l^32) only -> triggered max-reduce and
//    deferred l-reduce are a single shfl_xor(32).
__global__ __launch_bounds__(256, 2)
void attn_mfma_kernel(const _Float16* __restrict__ qh, const _Float16* __restrict__ kh,
                      const _Float16* __restrict__ vtg, _Float16* __restrict__ aoh)
{
    __shared__ __align__(16) _Float16 Kb[2][2][64 * 96];   // [pair][buf], 48 KB
    __shared__ __align__(16) _Float16 Vt[2][96][64];       // [pair], 24 KB, XOR chunks

    const int tid  = threadIdx.x;      // 0..255
    const int wid  = tid >> 6;         // 0..3
    const int p    = wid >> 1;         // KV half this wave-pair owns
    const int wp   = wid & 1;          // wave within pair
    const int lane = tid & 63;
    const int rloc = lane & 31;        // MFMA row/col index
    const int hi   = lane >> 5;        // lane half
    const int r7   = rloc & 7;
    const int hi4  = hi * 4;
    const int h    = blockIdx.y;
    const int q0   = blockIdx.x * 64;
    const float scale_ = 0.10206207261596577f * 1.4426950408889634f;  // 1/sqrt(96)*log2e
    const int NT = (S_LEN / 2) / 64;   // 24 tiles per pair

    // Q fragments (B-operand of 32x32x16): col=l&31=own q-row, k=(l>>5)*8+j
    const _Float16* qrow = qh + (((size_t)h * S_LEN) + q0 + wp * 32 + rloc) * HDIM;
    half8 aq[6];
#pragma unroll
    for (int kc = 0; kc < 6; kc++) {
        half8 a = *(const half8*)&qrow[kc * 16 + 8 * hi];
        half8 v;
#pragma unroll
        for (int i = 0; i < 8; i++) v[i] = (_Float16)((float)a[i] * scale_);
        aq[kc] = v;
    }

    f32x16 o32[3];
#pragma unroll
    for (int d = 0; d < 3; d++)
#pragma unroll
        for (int i = 0; i < 16; i++) o32[d][i] = 0.f;
    float m_ = -INFINITY, l_ = 0.f;    // l_ per-lane partial (covers lane's kv subset)

    const char* kbase = (const char*)(kh + ((size_t)h * S_LEN + p * (S_LEN / 2)) * HDIM);

    // K staging precompute (R3/R4-proven): wave-inst i covers phys chunks
    // pc = i*128 + (tid&127); phys (row r=pc/12, cc=pc%12) holds logical (cc-r) mod 12.
    int koffb[6];
#pragma unroll
    for (int i = 0; i < 6; i++) {
        int pc = i * 128 + (tid & 127);
        int r  = pc / 12, c = pc - r * 12;
        int rm = r % 12;
        int cl = c - rm; if (cl < 0) cl += 12;
        koffb[i] = r * 192 + cl * 16;
    }
    // QK read offsets: row r = kvb*32+rloc, logical chunk hi+2kc, phys=(lc+r)%12
    int koffA[6], koffB[6];
#pragma unroll
    for (int kc = 0; kc < 6; kc++) {
        int rA = rloc,      pA = (hi + 2 * kc + rA) % 12;
        int rB = 32 + rloc, pB = (hi + 2 * kc + rB) % 12;
        koffA[kc] = rA * 192 + pA * 16;
        koffB[kc] = rB * 192 + pB * 16;
    }

    // V staging: pair-local thread tp -> d-row (tp>>3)+16u, chunk vc=tp&7,
    // phys slot = vc ^ (row&7)  (16u keeps row&7 invariant)
    const int tp = tid & 127;
    const int vd0 = tp >> 3, vc = tp & 7;
    const _Float16* vsrc0 = vtg + (size_t)h * HDIM * S_LEN + (size_t)vd0 * S_LEN
                          + p * (S_LEN / 2) + vc * 8;
    _Float16* vdst = &Vt[p][vd0][(vc ^ (vd0 & 7)) * 8];

    // ---- prologue: stage tile 0 (K via DMA, V via pinned regs) ----
#pragma unroll
    for (int i = 0; i < 6; i++)
        gload16(kbase + koffb[i], &Kb[p][0][i * 1024 + wp * 512]);
    uint4 vp0, vp1, vp2, vp3, vp4, vp5;
    vp0 = gld128(vsrc0 + 0 * 16 * S_LEN);
    vp1 = gld128(vsrc0 + 1 * 16 * S_LEN);
    vp2 = gld128(vsrc0 + 2 * 16 * S_LEN);
    vp3 = gld128(vsrc0 + 3 * 16 * S_LEN);
    vp4 = gld128(vsrc0 + 4 * 16 * S_LEN);
    vp5 = gld128(vsrc0 + 5 * 16 * S_LEN);
    asm volatile("s_waitcnt vmcnt(0)" ::: "memory");
    __builtin_amdgcn_sched_barrier(0);
    *(uint4*)(vdst + 0 * 16 * 64) = vp0;  *(uint4*)(vdst + 1 * 16 * 64) = vp1;
    *(uint4*)(vdst + 2 * 16 * 64) = vp2;  *(uint4*)(vdst + 3 * 16 * 64) = vp3;
    *(uint4*)(vdst + 4 * 16 * 64) = vp4;  *(uint4*)(vdst + 5 * 16 * 64) = vp5;
    __syncthreads();

    for (int kt = 0; kt < NT; ++kt) {
        const int cur = kt & 1;
        // issue next tile's K DMA (other buffer) and V pinned loads
        if (kt + 1 < NT) {
            const char* ks2 = kbase + (size_t)(kt + 1) * 12288;
#pragma unroll
            for (int i = 0; i < 6; i++)
                gload16(ks2 + koffb[i], &Kb[p][cur ^ 1][i * 1024 + wp * 512]);
            const _Float16* vs2 = vsrc0 + (kt + 1) * 64;
            vp0 = gld128(vs2 + 0 * 16 * S_LEN);
            vp1 = gld128(vs2 + 1 * 16 * S_LEN);
            vp2 = gld128(vs2 + 2 * 16 * S_LEN);
            vp3 = gld128(vs2 + 3 * 16 * S_LEN);
            vp4 = gld128(vs2 + 4 * 16 * S_LEN);
            vp5 = gld128(vs2 + 5 * 16 * S_LEN);
            __builtin_amdgcn_sched_barrier(0);
        }

        // ---- QK: S^T[kv32][q32], two kv-blocks, 6 hd-chunks each ----
        const char* Kc = (const char*)&Kb[p][cur][0];
        f32x16 sA, sB;
#pragma unroll
        for (int i = 0; i < 16; i++) { sA[i] = 0.f; sB[i] = 0.f; }
#pragma unroll
        for (int kc = 0; kc < 6; kc++) {
            half8 ka = *(const half8*)(Kc + koffA[kc]);
            half8 kb = *(const half8*)(Kc + koffB[kc]);
            sA = __builtin_amdgcn_mfma_f32_32x32x16_f16(ka, aq[kc], sA, 0, 0, 0);
            sB = __builtin_amdgcn_mfma_f32_32x32x16_f16(kb, aq[kc], sB, 0, 0, 0);
        }

        // ---- online softmax (log2 domain, defer-max THR=8) ----
        float mx = sA[0];
#pragma unroll
        for (int i = 1; i < 16; i++) mx = fmaxf(mx, sA[i]);
#pragma unroll
        for (int i = 0; i < 16; i++) mx = fmaxf(mx, sB[i]);
        if (!__all(mx <= m_ + 8.0f)) {
            mx = fmaxf(mx, __shfl_xor(mx, 32));
            float mn = fmaxf(m_, mx);
            float al = __builtin_amdgcn_exp2f(m_ - mn);
            m_ = mn; l_ *= al;
#pragma unroll
            for (int d = 0; d < 3; d++)
#pragma unroll
                for (int i = 0; i < 16; i++) o32[d][i] *= al;
        }
        float rs = 0.f;
#pragma unroll
        for (int i = 0; i < 16; i++) {
            float e = __builtin_amdgcn_exp2f(sA[i] - m_); sA[i] = e; rs += e;
        }
#pragma unroll
        for (int i = 0; i < 16; i++) {
            float e = __builtin_amdgcn_exp2f(sB[i] - m_); sB[i] = e; rs += e;
        }
        l_ += rs;

        // ---- P frags: 32x32x8 B-operand k-subset == lane's own kv subset ----
        half4v pf[8];
#pragma unroll
        for (int t = 0; t < 4; t++) {
            half4v v0, v1;
            v0[0] = (_Float16)sA[4 * t + 0]; v0[1] = (_Float16)sA[4 * t + 1];
            v0[2] = (_Float16)sA[4 * t + 2]; v0[3] = (_Float16)sA[4 * t + 3];
            v1[0] = (_Float16)sB[4 * t + 0]; v1[1] = (_Float16)sB[4 * t + 1];
            v1[2] = (_Float16)sB[4 * t + 2]; v1[3] = (_Float16)sB[4 * t + 3];
            pf[t]     = v0;
            pf[4 + t] = v1;
        }

        // ---- PV: 8 kv8-blocks x 3 d-blocks of 32x32x8 ----
#pragma unroll
        for (int nb8 = 0; nb8 < 8; nb8++) {
            const int co = ((nb8 ^ r7) << 3) + hi4;
#pragma unroll
            for (int d = 0; d < 3; d++) {
                half4v av = *(const half4v*)&Vt[p][d * 32 + rloc][co];
                o32[d] = __builtin_amdgcn_mfma_f32_32x32x8f16(av, pf[nb8], o32[d], 0, 0, 0);
            }
        }

        __syncthreads();   // B: Vt/Kb reads done; K[t+1] DMA drained (tracked)
        asm volatile("s_waitcnt vmcnt(0)" ::: "memory");  // V[t+1] pinned regs arrived
        __builtin_amdgcn_sched_barrier(0);
        if (kt + 1 < NT) {
            *(uint4*)(vdst + 0 * 16 * 64) = vp0;  *(uint4*)(vdst + 1 * 16 * 64) = vp1;
            *(uint4*)(vdst + 2 * 16 * 64) = vp2;  *(uint4*)(vdst + 3 * 16 * 64) = vp3;
            *(uint4*)(vdst + 4 * 16 * 64) = vp4;  *(uint4*)(vdst + 5 * 16 * 64) = vp5;
        }
        __syncthreads();   // A: V[t+1] visible to pair partner
    }

    // ---- cross-pair merge through LDS (overlays Kb; all tile work done) ----
    const float lt = l_ + __shfl_xor(l_, 32);   // finish deferred l reduction
    const int qrl = wp * 32 + rloc;             // 0..63 within block
    float*  scr = (float*)&Kb[0][0][0];                    // 64 x 100 f32 (25.6 KB)
    float2* mlb = (float2*)((char*)&Kb[0][0][0] + 26624);  // 64 x {m,l}
    if (p == 1) {
        if (hi == 0) mlb[qrl] = make_float2(m_, lt);
#pragma unroll
        for (int d = 0; d < 3; d++)
#pragma unroll
            for (int b2 = 0; b2 < 4; b2++) {
                f32x4 c4 = { o32[d][4 * b2 + 0], o32[d][4 * b2 + 1],
                             o32[d][4 * b2 + 2], o32[d][4 * b2 + 3] };
                *(f32x4*)&scr[qrl * 100 + d * 32 + 8 * b2 + hi4] = c4;
            }
    }
    __syncthreads();
    if (p == 0) {
        float2 ml1 = mlb[qrl];
        float mm = fmaxf(m_, ml1.x);
        float a0 = __builtin_amdgcn_exp2f(m_ - mm);
        float a1 = __builtin_amdgcn_exp2f(ml1.x - mm);
        float li = 1.0f / (lt * a0 + ml1.y * a1);
        const size_t rowbase = (size_t)(q0 + qrl) * DIM + h * HDIM;
#pragma unroll
        for (int d = 0; d < 3; d++)
#pragma unroll
            for (int b2 = 0; b2 < 4; b2++) {
                f32x4 o1 = *(const f32x4*)&scr[qrl * 100 + d * 32 + 8 * b2 + hi4];
                half4v pk;
#pragma unroll
                for (int r = 0; r < 4; r++)
                    pk[r] = (_Float16)((o32[d][4 * b2 + r] * a0 + o1[r] * a1) * li);
                *(half4v*)&aoh[rowbase + d * 32 + 8 * b2 + hi4] = pk;
            }
    }
}

extern "C" void kernel_launch(void* const* d_in, const int* in_sizes, int n_in,
                              void* d_out, int out_size, void* d_ws, size_t ws_size,
                              hipStream_t stream) {
    const float* x  = (const float*)d_in[0];
    const float* wq = (const float*)d_in[1];
    const float* bq = (const float*)d_in[2];
    const float* wk = (const float*)d_in[3];
    const float* bk = (const float*)d_in[4];
    const float* wv = (const float*)d_in[5];
    const float* bv = (const float*)d_in[6];
    const float* wo = (const float*)d_in[7];
    const float* bo = (const float*)d_in[8];
    const float* fc = (const float*)d_in[9];
    const float* fs = (const float*)d_in[10];
    float* out = (float*)d_out;

    const size_t per  = (size_t)NHEADS * S_LEN * HDIM;   // 4,718,592
    const size_t dim2 = (size_t)DIM * DIM;               // 2,359,296
    _Float16* hws  = (_Float16*)d_ws;
    _Float16* qkvh = hws;                 // q,k fp16 [head][s][hd] (roped); v fp16 [head][hd][s]
    _Float16* qh   = qkvh;
    _Float16* kh   = qkvh + per;
    _Float16* vth  = qkvh + 2 * per;
    _Float16* xh   = hws + 3 * per;       // x fp16; later reused as ao fp16
    _Float16* wth  = hws + 4 * per;       // 4 transposed weights fp16

    convert_f32_f16<<<(int)((S_LEN * DIM / 4 + 255) / 256), 256, 0, stream>>>(
        x, xh, S_LEN * DIM / 4);
    transpose_w<<<dim3(DIM / 64, DIM / 64, 4), 256, 0, stream>>>(wq, wk, wv, wo, wth);

    // fused QKV projection + RoPE -> fp16
    gemm_f16<true><<<dim3(DIM / 128, S_LEN / 128, 3), 256, 0, stream>>>(
        xh, wth, wth + dim2, wth + 2 * dim2, bq, bk, bv, fc, fs, qkvh);
    attn_mfma_kernel<<<dim3(S_LEN / 64, NHEADS), 256, 0, stream>>>(qh, kh, vth, xh);
    gemm_f16<false><<<dim3(DIM / 128, S_LEN / 128, 1), 256, 0, stream>>>(
        xh, wth + 3 * dim2, nullptr, nullptr, bo, nullptr, nullptr, fc, fs, out);
}